// Round 2
// baseline (81.242 us; speedup 1.0000x reference)
//
#include <hip/hip_runtime.h>

// Problem constants (from reference): B=8, N=512, F=16, D=20, GAMMA=10, mu_k = k*0.1
#define NATOMS 512
#define ND     20
#define NF     16
#define GAMMA_F 10.0f

// Algebraic collapse (only n=0 of the (B,N,N,F) tensor reaches the output):
//   out[b] = Q_b + sum_f Q_w[f] * ( emb_f + x_f * ( sum_d S[b,d]*Wc_w[f,d] + (N-1)*Wc_b[f] ) )
//   x_f    = Wi_b[f] + sum_g emb_g * Wi_w[f*F+g]        (emb identical for all b,m)
//   S[b,d] = sum_{m=1..N-1} exp(-GAMMA*(dist(b,0,m) - 0.1*d)^2)

__global__ __launch_bounds__(256) void schnet_row0_kernel(
    const float* __restrict__ coords,    // (B, N, 3)
    const float* __restrict__ atom_emb,  // (1, 1, F)
    const float* __restrict__ Wc_w,      // (F, D)
    const float* __restrict__ Wc_b,      // (F,)
    const float* __restrict__ Wi_w,      // (F, F)
    const float* __restrict__ Wi_b,      // (F,)
    const float* __restrict__ Q_w,       // (1, F)
    const float* __restrict__ Q_b,       // (1,)
    float* __restrict__ out)             // (B, 1)
{
    const int b   = blockIdx.x;
    const int tid = threadIdx.x;

    __shared__ float S_sh[ND];
    if (tid < ND) S_sh[tid] = 0.0f;
    __syncthreads();

    const float* cb = coords + (size_t)b * NATOMS * 3;
    const float c0x = cb[0];
    const float c0y = cb[1];
    const float c0z = cb[2];

    float s[ND];
#pragma unroll
    for (int k = 0; k < ND; ++k) s[k] = 0.0f;

    // Each thread covers atoms m = tid, tid+256 (skip the masked diagonal m==0).
    for (int m = tid; m < NATOMS; m += 256) {
        if (m == 0) continue;
        const float dx = cb[3 * m + 0] - c0x;
        const float dy = cb[3 * m + 1] - c0y;
        const float dz = cb[3 * m + 2] - c0z;
        const float d2 = dx * dx + dy * dy + dz * dz;
        const float adj = (d2 > 0.0f) ? sqrtf(d2) : 0.0f;   // reference's d2>0 guard
#pragma unroll
        for (int k = 0; k < ND; ++k) {
            const float t = adj - 0.1f * (float)k;
            s[k] += __expf(-GAMMA_F * t * t);
        }
    }

    // Reduce 20 partial sums: wave-64 shuffle tree, one LDS atomic per wave per k.
#pragma unroll
    for (int k = 0; k < ND; ++k) {
        float v = s[k];
#pragma unroll
        for (int off = 32; off > 0; off >>= 1)
            v += __shfl_down(v, off, 64);
        if ((tid & 63) == 0) atomicAdd(&S_sh[k], v);
    }
    __syncthreads();

    if (tid == 0) {
        float emb[NF];
#pragma unroll
        for (int f = 0; f < NF; ++f) emb[f] = atom_emb[f];

        float acc = Q_b[0];
#pragma unroll
        for (int f = 0; f < NF; ++f) {
            // x_f = Wi_b[f] + sum_g emb_g * Wi_w[f,g]   (einsum 'bmf,gf->bmg')
            float xf = Wi_b[f];
#pragma unroll
            for (int g = 0; g < NF; ++g)
                xf += emb[g] * Wi_w[f * NF + g];

            // T_f = sum_d S[d]*Wc_w[f,d] + (N-1)*Wc_b[f]
            float T = (float)(NATOMS - 1) * Wc_b[f];
#pragma unroll
            for (int k = 0; k < ND; ++k)
                T += S_sh[k] * Wc_w[f * ND + k];

            const float v0 = emb[f] + T * xf;   // v[:,0,:] = emb + msg
            acc += Q_w[f] * v0;
        }
        out[b] = acc;
    }
}

extern "C" void kernel_launch(void* const* d_in, const int* in_sizes, int n_in,
                              void* d_out, int out_size, void* d_ws, size_t ws_size,
                              hipStream_t stream) {
    const float* coords   = (const float*)d_in[0];
    const float* atom_emb = (const float*)d_in[1];
    const float* Wc_w     = (const float*)d_in[2];
    const float* Wc_b     = (const float*)d_in[3];
    const float* Wi_w     = (const float*)d_in[4];
    const float* Wi_b     = (const float*)d_in[5];
    const float* Q_w      = (const float*)d_in[6];
    const float* Q_b      = (const float*)d_in[7];
    float* out            = (float*)d_out;

    const int B = in_sizes[0] / (NATOMS * 3);   // 8

    schnet_row0_kernel<<<dim3(B), dim3(256), 0, stream>>>(
        coords, atom_emb, Wc_w, Wc_b, Wi_w, Wi_b, Q_w, Q_b, out);
}